// Round 6
// baseline (418.471 us; speedup 1.0000x reference)
//
#include <hip/hip_runtime.h>
#include <hip/hip_bf16.h>
#include <cstdint>

#define H 1024
#define F 2048
#define E 8
#define T_TOK 4096
#define NPAIR (T_TOK * 2)   // top-2 per token
#define BK 32               // K-step per LDS tile
#define TM2 32              // m-tiles of 128 per expert (4096/128)
#define NB 16               // hist blocks (NB*256 == T_TOK)

typedef __attribute__((ext_vector_type(8))) short short8;
typedef __attribute__((ext_vector_type(4))) float f32x4;

__device__ __forceinline__ ushort f2bf(float f) {
  uint32_t u = __builtin_bit_cast(uint32_t, f);
  u += 0x7FFF + ((u >> 16) & 1);   // RNE
  return (ushort)(u >> 16);
}

// async global->LDS, 16B per lane; LDS dest = wave-uniform base + lane*16
__device__ __forceinline__ void async_copy16(const ushort* g, ushort* l) {
  __builtin_amdgcn_global_load_lds(
      (const __attribute__((address_space(1))) unsigned int*)g,
      (__attribute__((address_space(3))) unsigned int*)l, 16, 0, 0);
}

// ---------------- router: fp32 logits, softmax, top-2; ALSO casts x->bf16 ----
__global__ __launch_bounds__(256) void router_kernel(
    const float* __restrict__ x, const float* __restrict__ gw,
    float* __restrict__ logits_out, int* __restrict__ sel,
    float* __restrict__ selw, ushort* __restrict__ xb) {
  int tid = threadIdx.x;
  int t = blockIdx.x * 4 + (tid >> 6);   // one wave per token
  int l = tid & 63;
  const float4* xr = (const float4*)(x + (size_t)t * H);
  const float4* g4 = (const float4*)gw;
  float acc[E];
#pragma unroll
  for (int e = 0; e < E; ++e) acc[e] = 0.f;
  float4 xs[4];
#pragma unroll
  for (int i = 0; i < 4; ++i) {
    float4 xv = xr[l + 64 * i];
    xs[i] = xv;
#pragma unroll
    for (int e = 0; e < E; ++e) {
      float4 gv = g4[e * (H / 4) + l + 64 * i];
      acc[e] += xv.x * gv.x + xv.y * gv.y + xv.z * gv.z + xv.w * gv.w;
    }
  }
  // fused cast: x row -> bf16 (replaces cast_x_kernel; saves a 16MB re-read)
#pragma unroll
  for (int i = 0; i < 4; ++i) {
    ushort4 o = make_ushort4(f2bf(xs[i].x), f2bf(xs[i].y), f2bf(xs[i].z), f2bf(xs[i].w));
    *(ushort4*)(xb + (size_t)t * H + (l + 64 * i) * 4) = o;
  }
#pragma unroll
  for (int off = 32; off > 0; off >>= 1)
#pragma unroll
    for (int e = 0; e < E; ++e) acc[e] += __shfl_xor(acc[e], off, 64);

  if (l == 0) {
    float m = acc[0];
    for (int e = 1; e < E; ++e) m = fmaxf(m, acc[e]);
    float p[E], den = 0.f;
    for (int e = 0; e < E; ++e) { p[e] = __expf(acc[e] - m); den += p[e]; }
    float inv = 1.f / den;
    int i0 = 0;
    for (int e = 1; e < E; ++e) if (acc[e] > acc[i0]) i0 = e;
    int i1 = (i0 == 0) ? 1 : 0;
    for (int e = 0; e < E; ++e) if (e != i0 && acc[e] > acc[i1]) i1 = e;
    for (int e = 0; e < E; ++e) logits_out[t * E + e] = acc[e];
    sel[t * 2] = i0; sel[t * 2 + 1] = i1;
    selw[t * 2] = p[i0] * inv; selw[t * 2 + 1] = p[i1] * inv;
  }
}

// ---------------- hist: per-256-token-block LDS histogram + local ranks ------
__global__ __launch_bounds__(256) void hist_kernel(
    const int* __restrict__ sel, int* __restrict__ lrank,
    int* __restrict__ blkcnt) {
  __shared__ int h[E];
  int tid = threadIdx.x, b = blockIdx.x;
  if (tid < E) h[tid] = 0;
  __syncthreads();
  int t = b * 256 + tid;
  int e0 = sel[t * 2], e1 = sel[t * 2 + 1];
  lrank[t * 2] = atomicAdd(&h[e0], 1);
  lrank[t * 2 + 1] = atomicAdd(&h[e1], 1);
  __syncthreads();
  if (tid < E) blkcnt[b * E + tid] = h[tid];
}

// ---------------- offsets: counts, expert offsets, per-(block,expert) bases --
__global__ __launch_bounds__(128) void offsets_kernel(
    const int* __restrict__ blkcnt, int* __restrict__ counts,
    int* __restrict__ offsets, int* __restrict__ blkbase) {
  __shared__ int c[NB * E];
  __shared__ int tot[E], off[E];
  int tid = threadIdx.x;              // tid = b*E + e, 128 threads
  c[tid] = blkcnt[tid];
  __syncthreads();
  int b = tid >> 3, e = tid & 7;
  int pre = 0;
  for (int bb = 0; bb < b; ++bb) pre += c[bb * E + e];
  if (b == NB - 1) tot[e] = pre + c[tid];
  __syncthreads();
  if (tid == 0) {
    int s = 0;
    for (int ee = 0; ee < E; ++ee) {
      off[ee] = s; offsets[ee] = s; counts[ee] = tot[ee]; s += tot[ee];
    }
  }
  __syncthreads();
  blkbase[tid] = off[e] + pre;
}

// ---------------- scatter: slot = blkbase + lrank (no atomics) ---------------
__global__ __launch_bounds__(256) void scatter_kernel(
    const int* __restrict__ sel, const float* __restrict__ selw,
    const int* __restrict__ lrank, const int* __restrict__ blkbase,
    int* __restrict__ pair_token, float* __restrict__ pair_weight,
    int* __restrict__ pair_slot) {
  int tid = threadIdx.x, b = blockIdx.x;
  int t = b * 256 + tid;
#pragma unroll
  for (int k = 0; k < 2; ++k) {
    int e = sel[t * 2 + k];
    int slot = blkbase[b * E + e] + lrank[t * 2 + k];
    pair_token[slot] = t;
    pair_weight[slot] = selw[t * 2 + k];
    pair_slot[t * 2 + k] = slot;
  }
}

// ---- weight transpose+cast: fp32 [e][R][C] -> bf16 [e][C][R] ----------------
__global__ __launch_bounds__(256) void transpose_cast13_kernel(
    const float* __restrict__ w1, const float* __restrict__ w3,
    ushort* __restrict__ w1t, ushort* __restrict__ w3t) {
  __shared__ ushort tile[64][65];
  int z = blockIdx.z;
  const float* src = (z < E ? w1 : w3) + (size_t)(z & 7) * H * F;
  ushort* dst = (z < E ? w1t : w3t) + (size_t)(z & 7) * H * F;
  const int R = H, C = F;
  int r0 = blockIdx.y * 64, c0 = blockIdx.x * 64;
  int tid = threadIdx.x;
  int tr = tid >> 4, tc = (tid & 15) * 4;
#pragma unroll
  for (int i = 0; i < 4; ++i) {
    float4 v = *(const float4*)(src + (size_t)(r0 + tr + 16 * i) * C + c0 + tc);
    tile[tr + 16 * i][tc + 0] = f2bf(v.x);
    tile[tr + 16 * i][tc + 1] = f2bf(v.y);
    tile[tr + 16 * i][tc + 2] = f2bf(v.z);
    tile[tr + 16 * i][tc + 3] = f2bf(v.w);
  }
  __syncthreads();
#pragma unroll
  for (int i = 0; i < 4; ++i) {
    int dr = tr + 16 * i;           // dest row = source col
    ushort4 o;
    o.x = tile[tc + 0][dr]; o.y = tile[tc + 1][dr];
    o.z = tile[tc + 2][dr]; o.w = tile[tc + 3][dr];
    *(ushort4*)(dst + (size_t)(c0 + dr) * R + r0 + tc) = o;
  }
}

__global__ __launch_bounds__(256) void transpose_cast_kernel(
    const float* __restrict__ src, ushort* __restrict__ dst, int R, int C) {
  __shared__ ushort tile[64][65];
  int e = blockIdx.z;
  src += (size_t)e * R * C;
  dst += (size_t)e * R * C;
  int r0 = blockIdx.y * 64, c0 = blockIdx.x * 64;
  int tid = threadIdx.x;
  int tr = tid >> 4, tc = (tid & 15) * 4;
#pragma unroll
  for (int i = 0; i < 4; ++i) {
    float4 v = *(const float4*)(src + (size_t)(r0 + tr + 16 * i) * C + c0 + tc);
    tile[tr + 16 * i][tc + 0] = f2bf(v.x);
    tile[tr + 16 * i][tc + 1] = f2bf(v.y);
    tile[tr + 16 * i][tc + 2] = f2bf(v.z);
    tile[tr + 16 * i][tc + 3] = f2bf(v.w);
  }
  __syncthreads();
#pragma unroll
  for (int i = 0; i < 4; ++i) {
    int dr = tr + 16 * i;           // dest row = source col
    ushort4 o;
    o.x = tile[tc + 0][dr]; o.y = tile[tc + 1][dr];
    o.z = tile[tc + 2][dr]; o.w = tile[tc + 3][dr];
    *(ushort4*)(dst + (size_t)(c0 + dr) * R + r0 + tc) = o;
  }
}

// ===================== GEMM tiles (verified 16x16 frag pattern) ==============
// LDS tile: 128 rows x BK(=32) k-elems, row-major, 64B/row (32 ushorts).
// Chunk swizzle: 16B slot s of row r holds k-chunk (s ^ ((r>>1)&3)) -> 0
// measured bank conflicts (rows 0..127, lr=l&15 groups). 2-phase dbuf.

__device__ __forceinline__ int frag_off(int rr, int lkb) {   // ushort offset
  return rr * 32 + ((lkb ^ ((rr >> 1) & 3)) * 8);
}

// ---------------- grouped GEMM A: h = silu(x@w1) * (x@w3) ----------------
// ROUND 6: 4 waves (256 thr), 128x128 tile, wave tile 64x64, dual accumulator
// (c1 AND c3 per wave). Per wave per K-step: 12 ds_read_b128 -> 32 MFMA
// (375 B LDS per MFMA vs 512 before; half the block LDS read traffic, half
// the barrier participants, same 128 MFMA/block-step). acc 32xf32x4 + frags
// ~210 VGPR -> 2 waves/SIMD -> 2 co-resident desynced blocks/CU preserved.
__global__ __launch_bounds__(256, 2) void gemm_h_kernel(
    const ushort* __restrict__ xb, const ushort* __restrict__ w1t,
    const ushort* __restrict__ w3t, const int* __restrict__ pair_token,
    const int* __restrict__ counts, const int* __restrict__ offsets,
    ushort* __restrict__ hbuf) {
  int e = blockIdx.x;                 // expert == XCD (affinity heuristic)
  int mt = blockIdx.y;
  int cnt = counts[e];
  int m0 = mt * 128;
  if (m0 >= cnt) return;
  int base = offsets[e];
  int f0 = blockIdx.z * 128;

  __shared__ ushort As[2][4096], B1s[2][4096], B3s[2][4096];   // 48 KB total

  int tid = threadIdx.x;
  int w = tid >> 6, l = tid & 63;     // w in 0..3
  int q = l >> 2, s = l & 3;

  // staging: wave w stages rows [w*16,w*16+16) and [64+w*16, 64+w*16+16)
  // of each of A, B1, B3 (6 async copies per step, 24KB/block-step)
  int r0 = w * 16 + q, r1 = r0 + 64;
  int g0 = s ^ ((r0 >> 1) & 3), g1 = s ^ ((r1 >> 1) & 3);

  int pA0 = base + m0 + r0; if (pA0 >= base + cnt) pA0 = base + cnt - 1;
  int pA1 = base + m0 + r1; if (pA1 >= base + cnt) pA1 = base + cnt - 1;
  const ushort* gA0 = xb + (size_t)pair_token[pA0] * H + g0 * 8;
  const ushort* gA1 = xb + (size_t)pair_token[pA1] * H + g1 * 8;
  const ushort* gB1a = w1t + ((size_t)e * F + f0 + r0) * H + g0 * 8;
  const ushort* gB1b = w1t + ((size_t)e * F + f0 + r1) * H + g1 * 8;
  const ushort* gB3a = w3t + ((size_t)e * F + f0 + r0) * H + g0 * 8;
  const ushort* gB3b = w3t + ((size_t)e * F + f0 + r1) * H + g1 * 8;
  int lofs0 = w * 512;                // row (w*16) * 32 ushorts
  int lofs1 = 2048 + w * 512;         // row (64+w*16) * 32 ushorts

  int wm = w >> 1, wn = w & 1;        // wave tile: rows wm*64+, cols wn*64+
  int lr = l & 15, lkb = l >> 4;

  int offA[4], offB[4];
#pragma unroll
  for (int ms = 0; ms < 4; ++ms) offA[ms] = frag_off(wm * 64 + ms * 16 + lr, lkb);
#pragma unroll
  for (int ns = 0; ns < 4; ++ns) offB[ns] = frag_off(wn * 64 + ns * 16 + lr, lkb);

  f32x4 c1[4][4], c3[4][4];
#pragma unroll
  for (int a = 0; a < 4; ++a)
#pragma unroll
    for (int b = 0; b < 4; ++b) { c1[a][b] = (f32x4)0.f; c3[a][b] = (f32x4)0.f; }

  // prologue: stage k-tile 0 into buffer 0
  async_copy16(gA0,  &As[0][lofs0]);
  async_copy16(gA1,  &As[0][lofs1]);
  async_copy16(gB1a, &B1s[0][lofs0]);
  async_copy16(gB1b, &B1s[0][lofs1]);
  async_copy16(gB3a, &B3s[0][lofs0]);
  async_copy16(gB3b, &B3s[0][lofs1]);
  gA0 += BK; gA1 += BK; gB1a += BK; gB1b += BK; gB3a += BK; gB3b += BK;
  __syncthreads();                    // vmcnt(0) drain -> buf0 valid

  int cur = 0;
  for (int k0 = 0; k0 < H; k0 += BK, cur ^= 1) {
    if (k0 + BK < H) {                // prefetch NEXT k-tile into other buffer
      int nb = cur ^ 1;
      async_copy16(gA0,  &As[nb][lofs0]);
      async_copy16(gA1,  &As[nb][lofs1]);
      async_copy16(gB1a, &B1s[nb][lofs0]);
      async_copy16(gB1b, &B1s[nb][lofs1]);
      async_copy16(gB3a, &B3s[nb][lofs0]);
      async_copy16(gB3b, &B3s[nb][lofs1]);
      gA0 += BK; gA1 += BK; gB1a += BK; gB1b += BK; gB3a += BK; gB3b += BK;
    }

    short8 af[4], b1f[4], b3f[4];
#pragma unroll
    for (int ms = 0; ms < 4; ++ms) af[ms] = *(const short8*)(&As[cur][0] + offA[ms]);
#pragma unroll
    for (int ns = 0; ns < 4; ++ns) {
      b1f[ns] = *(const short8*)(&B1s[cur][0] + offB[ns]);
      b3f[ns] = *(const short8*)(&B3s[cur][0] + offB[ns]);
    }
#pragma unroll
    for (int ms = 0; ms < 4; ++ms)
#pragma unroll
      for (int ns = 0; ns < 4; ++ns) {
        c1[ms][ns] = __builtin_amdgcn_mfma_f32_16x16x32_bf16(af[ms], b1f[ns], c1[ms][ns], 0, 0, 0);
        c3[ms][ns] = __builtin_amdgcn_mfma_f32_16x16x32_bf16(af[ms], b3f[ns], c3[ms][ns], 0, 0, 0);
      }
    __syncthreads();                  // drains prefetch vmcnt; swap buffers
  }

#pragma unroll
  for (int ms = 0; ms < 4; ++ms)
#pragma unroll
    for (int ns = 0; ns < 4; ++ns)
#pragma unroll
      for (int rg = 0; rg < 4; ++rg) {
        int ml = wm * 64 + ms * 16 + (l >> 4) * 4 + rg;   // C/D: row=(lane>>4)*4+reg
        if (m0 + ml < cnt) {
          int nl = wn * 64 + ns * 16 + (l & 15);          // col=lane&15
          float gg = c1[ms][ns][rg], u = c3[ms][ns][rg];
          float hv = gg / (1.f + __expf(-gg)) * u;        // silu(g)*u
          hbuf[(size_t)(base + m0 + ml) * F + f0 + nl] = f2bf(hv);
        }
      }
}

// ---------------- grouped GEMM B: po = weight * (h @ w2), per-pair rows -------
// (R5 form — control, unchanged: 4 waves, 128x128, wave 64x64, 16 MFMA/step)
__global__ __launch_bounds__(256) void gemm_out_kernel(
    const ushort* __restrict__ hbuf, const ushort* __restrict__ w2t,
    const float* __restrict__ pair_weight, const int* __restrict__ counts,
    const int* __restrict__ offsets, float* __restrict__ po) {
  int e = blockIdx.x;                 // expert == XCD
  int mt = blockIdx.y;
  int cnt = counts[e];
  int m0 = mt * 128;
  if (m0 >= cnt) return;
  int base = offsets[e];
  int n0 = blockIdx.z * 128;

  __shared__ ushort As[2][4096], Bs[2][4096];   // 32 KB
  __shared__ float wt_s[128];

  int tid = threadIdx.x;
  int w = tid >> 6, l = tid & 63;     // w in 0..3
  int q = l >> 2, s = l & 3;

  if (tid < 128) {
    int p = base + m0 + tid;
    if (p >= base + cnt) p = base + cnt - 1;
    wt_s[tid] = pair_weight[p];
  }

  // staging: wave w stages rows [w*32, w*32+32) of A and B (2 copies each)
  int r0 = w * 32 + q, r1 = r0 + 16;
  int g0 = s ^ ((r0 >> 1) & 3), g1 = s ^ ((r1 >> 1) & 3);
  int p0 = base + m0 + r0; if (p0 >= base + cnt) p0 = base + cnt - 1;
  int p1 = base + m0 + r1; if (p1 >= base + cnt) p1 = base + cnt - 1;
  const ushort* gAa = hbuf + (size_t)p0 * F + g0 * 8;
  const ushort* gAb = hbuf + (size_t)p1 * F + g1 * 8;
  const ushort* gBa = w2t + ((size_t)e * H + n0 + r0) * F + g0 * 8;
  const ushort* gBb = w2t + ((size_t)e * H + n0 + r1) * F + g1 * 8;
  int lofs = w * 1024;                // row (w*32) * 32 ushorts

  int wm = w >> 1, wn = w & 1;        // wave tile: rows wm*64+, cols wn*64+
  int lr = l & 15, lkb = l >> 4;

  int offA[4], offB[4];
#pragma unroll
  for (int ms = 0; ms < 4; ++ms) offA[ms] = frag_off(wm * 64 + ms * 16 + lr, lkb);
#pragma unroll
  for (int ns = 0; ns < 4; ++ns) offB[ns] = frag_off(wn * 64 + ns * 16 + lr, lkb);

  f32x4 cc[4][4];
#pragma unroll
  for (int a = 0; a < 4; ++a)
#pragma unroll
    for (int b = 0; b < 4; ++b) cc[a][b] = (f32x4)0.f;

  // prologue: stage k-tile 0 into buffer 0
  async_copy16(gAa, &As[0][lofs]);
  async_copy16(gAb, &As[0][lofs + 512]);
  async_copy16(gBa, &Bs[0][lofs]);
  async_copy16(gBb, &Bs[0][lofs + 512]);
  gAa += BK; gAb += BK; gBa += BK; gBb += BK;
  __syncthreads();

  int cur = 0;
  for (int k0 = 0; k0 < F; k0 += BK, cur ^= 1) {
    if (k0 + BK < F) {
      int nb = cur ^ 1;
      async_copy16(gAa, &As[nb][lofs]);
      async_copy16(gAb, &As[nb][lofs + 512]);
      async_copy16(gBa, &Bs[nb][lofs]);
      async_copy16(gBb, &Bs[nb][lofs + 512]);
      gAa += BK; gAb += BK; gBa += BK; gBb += BK;
    }

    short8 af[4], bf_[4];
#pragma unroll
    for (int ms = 0; ms < 4; ++ms) af[ms] = *(const short8*)(&As[cur][0] + offA[ms]);
#pragma unroll
    for (int ns = 0; ns < 4; ++ns) bf_[ns] = *(const short8*)(&Bs[cur][0] + offB[ns]);
#pragma unroll
    for (int ms = 0; ms < 4; ++ms)
#pragma unroll
      for (int ns = 0; ns < 4; ++ns)
        cc[ms][ns] = __builtin_amdgcn_mfma_f32_16x16x32_bf16(af[ms], bf_[ns], cc[ms][ns], 0, 0, 0);
    __syncthreads();
  }

#pragma unroll
  for (int ms = 0; ms < 4; ++ms)
#pragma unroll
    for (int ns = 0; ns < 4; ++ns)
#pragma unroll
      for (int rg = 0; rg < 4; ++rg) {
        int ml = wm * 64 + ms * 16 + (l >> 4) * 4 + rg;
        if (m0 + ml < cnt) {
          int nl = wn * 64 + ns * 16 + (l & 15);
          po[(size_t)(base + m0 + ml) * H + n0 + nl] = cc[ms][ns][rg] * wt_s[ml];
        }
      }
}

// ---------------- combine: y[t] = po[slot0] + po[slot1] ----------------
__global__ __launch_bounds__(256) void combine_kernel(
    const float* __restrict__ po, const int* __restrict__ pair_slot,
    float* __restrict__ y) {
  int idx = blockIdx.x * 256 + threadIdx.x;    // over T*H/4
  int t = idx >> 8;                            // H/4 = 256 float4 per token
  int c = (idx & 255) * 4;
  int s0 = pair_slot[t * 2], s1 = pair_slot[t * 2 + 1];
  float4 a = *(const float4*)(po + (size_t)s0 * H + c);
  float4 b = *(const float4*)(po + (size_t)s1 * H + c);
  float4 o = make_float4(a.x + b.x, a.y + b.y, a.z + b.z, a.w + b.w);
  *(float4*)(y + (size_t)t * H + c) = o;
}

extern "C" void kernel_launch(void* const* d_in, const int* in_sizes, int n_in,
                              void* d_out, int out_size, void* d_ws, size_t ws_size,
                              hipStream_t stream) {
  const float* x  = (const float*)d_in[0];
  const float* gw = (const float*)d_in[1];
  const float* w1 = (const float*)d_in[2];
  const float* w3 = (const float*)d_in[3];
  const float* w2 = (const float*)d_in[4];
  float* y = (float*)d_out;                       // [T, H] fp32
  float* logits_out = y + (size_t)T_TOK * H;      // [T, E] fp32 (output #2)

  char* ws = (char*)d_ws;
  size_t off = 0;
  auto alloc = [&](size_t bytes) {
    char* p = ws + off;
    off += (bytes + 255) & ~size_t(255);
    return p;
  };
  ushort* xb   = (ushort*)alloc((size_t)T_TOK * H * 2);
  ushort* w1t  = (ushort*)alloc((size_t)E * F * H * 2);
  ushort* w3t  = (ushort*)alloc((size_t)E * F * H * 2);
  ushort* w2t  = (ushort*)alloc((size_t)E * H * F * 2);
  ushort* hbuf = (ushort*)alloc((size_t)(NPAIR + 128) * F * 2);
  int*   pair_token  = (int*)alloc(NPAIR * 4);
  float* pair_weight = (float*)alloc(NPAIR * 4);
  int*   pair_slot   = (int*)alloc(NPAIR * 4);
  int*   sel   = (int*)alloc(T_TOK * 2 * 4);
  float* selw  = (float*)alloc(T_TOK * 2 * 4);
  int*   lrank = (int*)alloc(NPAIR * 4);
  int* counts  = (int*)alloc(E * 4);
  int* offsets = (int*)alloc(E * 4);
  int* blkcnt  = (int*)alloc(NB * E * 4);
  int* blkbase = (int*)alloc(NB * E * 4);
  // po aliases w1t: w1t (32 MB) is dead after gemm_h; po needs NPAIR*H*4 = 32 MB.
  float* po = (float*)w1t;

  router_kernel<<<T_TOK / 4, 256, 0, stream>>>(x, gw, logits_out, sel, selw, xb);
  hist_kernel<<<NB, 256, 0, stream>>>(sel, lrank, blkcnt);
  offsets_kernel<<<1, NB * E, 0, stream>>>(blkcnt, counts, offsets, blkbase);
  scatter_kernel<<<NB, 256, 0, stream>>>(sel, selw, lrank, blkbase,
                                         pair_token, pair_weight, pair_slot);
  transpose_cast13_kernel<<<dim3(F / 64, H / 64, 2 * E), 256, 0, stream>>>(w1, w3, w1t, w3t);
  transpose_cast_kernel<<<dim3(H / 64, F / 64, E), 256, 0, stream>>>(w2, w2t, F, H);
  gemm_h_kernel<<<dim3(E, TM2, F / 128), 256, 0, stream>>>(xb, w1t, w3t, pair_token,
                                                           counts, offsets, hbuf);
  gemm_out_kernel<<<dim3(E, TM2, H / 128), 256, 0, stream>>>(hbuf, w2t, pair_weight,
                                                             counts, offsets, po);
  combine_kernel<<<(T_TOK * H / 4) / 256, 256, 0, stream>>>(po, pair_slot, y);
}

// Round 7
// 405.422 us; speedup vs baseline: 1.0322x; 1.0322x over previous
//
#include <hip/hip_runtime.h>
#include <hip/hip_bf16.h>
#include <cstdint>

#define H 1024
#define F 2048
#define E 8
#define T_TOK 4096
#define NPAIR (T_TOK * 2)   // top-2 per token
#define BK 32               // K-step per LDS tile
#define TM2 32              // m-tiles of 128 per expert (4096/128)
#define NB 16               // hist blocks (NB*256 == T_TOK)

typedef __attribute__((ext_vector_type(8))) short short8;
typedef __attribute__((ext_vector_type(4))) float f32x4;

__device__ __forceinline__ ushort f2bf(float f) {
  uint32_t u = __builtin_bit_cast(uint32_t, f);
  u += 0x7FFF + ((u >> 16) & 1);   // RNE
  return (ushort)(u >> 16);
}

// async global->LDS, 16B per lane; LDS dest = wave-uniform base + lane*16
__device__ __forceinline__ void async_copy16(const ushort* g, ushort* l) {
  __builtin_amdgcn_global_load_lds(
      (const __attribute__((address_space(1))) unsigned int*)g,
      (__attribute__((address_space(3))) unsigned int*)l, 16, 0, 0);
}

// ---------------- router: fp32 logits, softmax, top-2; ALSO casts x->bf16 ----
__global__ __launch_bounds__(256) void router_kernel(
    const float* __restrict__ x, const float* __restrict__ gw,
    float* __restrict__ logits_out, int* __restrict__ sel,
    float* __restrict__ selw, ushort* __restrict__ xb) {
  int tid = threadIdx.x;
  int t = blockIdx.x * 4 + (tid >> 6);   // one wave per token
  int l = tid & 63;
  const float4* xr = (const float4*)(x + (size_t)t * H);
  const float4* g4 = (const float4*)gw;
  float acc[E];
#pragma unroll
  for (int e = 0; e < E; ++e) acc[e] = 0.f;
  float4 xs[4];
#pragma unroll
  for (int i = 0; i < 4; ++i) {
    float4 xv = xr[l + 64 * i];
    xs[i] = xv;
#pragma unroll
    for (int e = 0; e < E; ++e) {
      float4 gv = g4[e * (H / 4) + l + 64 * i];
      acc[e] += xv.x * gv.x + xv.y * gv.y + xv.z * gv.z + xv.w * gv.w;
    }
  }
  // fused cast: x row -> bf16 (replaces cast_x_kernel; saves a 16MB re-read)
#pragma unroll
  for (int i = 0; i < 4; ++i) {
    ushort4 o = make_ushort4(f2bf(xs[i].x), f2bf(xs[i].y), f2bf(xs[i].z), f2bf(xs[i].w));
    *(ushort4*)(xb + (size_t)t * H + (l + 64 * i) * 4) = o;
  }
#pragma unroll
  for (int off = 32; off > 0; off >>= 1)
#pragma unroll
    for (int e = 0; e < E; ++e) acc[e] += __shfl_xor(acc[e], off, 64);

  if (l == 0) {
    float m = acc[0];
    for (int e = 1; e < E; ++e) m = fmaxf(m, acc[e]);
    float p[E], den = 0.f;
    for (int e = 0; e < E; ++e) { p[e] = __expf(acc[e] - m); den += p[e]; }
    float inv = 1.f / den;
    int i0 = 0;
    for (int e = 1; e < E; ++e) if (acc[e] > acc[i0]) i0 = e;
    int i1 = (i0 == 0) ? 1 : 0;
    for (int e = 0; e < E; ++e) if (e != i0 && acc[e] > acc[i1]) i1 = e;
    for (int e = 0; e < E; ++e) logits_out[t * E + e] = acc[e];
    sel[t * 2] = i0; sel[t * 2 + 1] = i1;
    selw[t * 2] = p[i0] * inv; selw[t * 2 + 1] = p[i1] * inv;
  }
}

// ---------------- hist: per-256-token-block LDS histogram + local ranks ------
__global__ __launch_bounds__(256) void hist_kernel(
    const int* __restrict__ sel, int* __restrict__ lrank,
    int* __restrict__ blkcnt) {
  __shared__ int h[E];
  int tid = threadIdx.x, b = blockIdx.x;
  if (tid < E) h[tid] = 0;
  __syncthreads();
  int t = b * 256 + tid;
  int e0 = sel[t * 2], e1 = sel[t * 2 + 1];
  lrank[t * 2] = atomicAdd(&h[e0], 1);
  lrank[t * 2 + 1] = atomicAdd(&h[e1], 1);
  __syncthreads();
  if (tid < E) blkcnt[b * E + tid] = h[tid];
}

// ---------------- offsets: counts, expert offsets, per-(block,expert) bases --
__global__ __launch_bounds__(128) void offsets_kernel(
    const int* __restrict__ blkcnt, int* __restrict__ counts,
    int* __restrict__ offsets, int* __restrict__ blkbase) {
  __shared__ int c[NB * E];
  __shared__ int tot[E], off[E];
  int tid = threadIdx.x;              // tid = b*E + e, 128 threads
  c[tid] = blkcnt[tid];
  __syncthreads();
  int b = tid >> 3, e = tid & 7;
  int pre = 0;
  for (int bb = 0; bb < b; ++bb) pre += c[bb * E + e];
  if (b == NB - 1) tot[e] = pre + c[tid];
  __syncthreads();
  if (tid == 0) {
    int s = 0;
    for (int ee = 0; ee < E; ++ee) {
      off[ee] = s; offsets[ee] = s; counts[ee] = tot[ee]; s += tot[ee];
    }
  }
  __syncthreads();
  blkbase[tid] = off[e] + pre;
}

// ---------------- scatter: slot = blkbase + lrank (no atomics) ---------------
__global__ __launch_bounds__(256) void scatter_kernel(
    const int* __restrict__ sel, const float* __restrict__ selw,
    const int* __restrict__ lrank, const int* __restrict__ blkbase,
    int* __restrict__ pair_token, float* __restrict__ pair_weight,
    int* __restrict__ pair_slot) {
  int tid = threadIdx.x, b = blockIdx.x;
  int t = b * 256 + tid;
#pragma unroll
  for (int k = 0; k < 2; ++k) {
    int e = sel[t * 2 + k];
    int slot = blkbase[b * E + e] + lrank[t * 2 + k];
    pair_token[slot] = t;
    pair_weight[slot] = selw[t * 2 + k];
    pair_slot[t * 2 + k] = slot;
  }
}

// ---- weight transpose+cast: fp32 [e][R][C] -> bf16 [e][C][R] ----------------
__global__ __launch_bounds__(256) void transpose_cast13_kernel(
    const float* __restrict__ w1, const float* __restrict__ w3,
    ushort* __restrict__ w1t, ushort* __restrict__ w3t) {
  __shared__ ushort tile[64][65];
  int z = blockIdx.z;
  const float* src = (z < E ? w1 : w3) + (size_t)(z & 7) * H * F;
  ushort* dst = (z < E ? w1t : w3t) + (size_t)(z & 7) * H * F;
  const int R = H, C = F;
  int r0 = blockIdx.y * 64, c0 = blockIdx.x * 64;
  int tid = threadIdx.x;
  int tr = tid >> 4, tc = (tid & 15) * 4;
#pragma unroll
  for (int i = 0; i < 4; ++i) {
    float4 v = *(const float4*)(src + (size_t)(r0 + tr + 16 * i) * C + c0 + tc);
    tile[tr + 16 * i][tc + 0] = f2bf(v.x);
    tile[tr + 16 * i][tc + 1] = f2bf(v.y);
    tile[tr + 16 * i][tc + 2] = f2bf(v.z);
    tile[tr + 16 * i][tc + 3] = f2bf(v.w);
  }
  __syncthreads();
#pragma unroll
  for (int i = 0; i < 4; ++i) {
    int dr = tr + 16 * i;           // dest row = source col
    ushort4 o;
    o.x = tile[tc + 0][dr]; o.y = tile[tc + 1][dr];
    o.z = tile[tc + 2][dr]; o.w = tile[tc + 3][dr];
    *(ushort4*)(dst + (size_t)(c0 + dr) * R + r0 + tc) = o;
  }
}

__global__ __launch_bounds__(256) void transpose_cast_kernel(
    const float* __restrict__ src, ushort* __restrict__ dst, int R, int C) {
  __shared__ ushort tile[64][65];
  int e = blockIdx.z;
  src += (size_t)e * R * C;
  dst += (size_t)e * R * C;
  int r0 = blockIdx.y * 64, c0 = blockIdx.x * 64;
  int tid = threadIdx.x;
  int tr = tid >> 4, tc = (tid & 15) * 4;
#pragma unroll
  for (int i = 0; i < 4; ++i) {
    float4 v = *(const float4*)(src + (size_t)(r0 + tr + 16 * i) * C + c0 + tc);
    tile[tr + 16 * i][tc + 0] = f2bf(v.x);
    tile[tr + 16 * i][tc + 1] = f2bf(v.y);
    tile[tr + 16 * i][tc + 2] = f2bf(v.z);
    tile[tr + 16 * i][tc + 3] = f2bf(v.w);
  }
  __syncthreads();
#pragma unroll
  for (int i = 0; i < 4; ++i) {
    int dr = tr + 16 * i;           // dest row = source col
    ushort4 o;
    o.x = tile[tc + 0][dr]; o.y = tile[tc + 1][dr];
    o.z = tile[tc + 2][dr]; o.w = tile[tc + 3][dr];
    *(ushort4*)(dst + (size_t)(c0 + dr) * R + r0 + tc) = o;
  }
}

// ===================== GEMM tiles (verified 16x16 frag pattern) ==============
// LDS tile: 128 rows x BK(=32) k-elems, row-major, 64B/row (32 ushorts).
// Chunk swizzle: 16B slot s of row r holds k-chunk (s ^ ((r>>1)&3)) -> 0
// measured bank conflicts. R7: 3-buffer distance-2 pipeline with COUNTED
// vmcnt + raw s_barrier (T4): the old __syncthreads drained vmcnt(0), waiting
// on the just-issued next-tile loads every K-step (invariant MfmaUtil 23%
// across R0/R1/R5/R6 = exposed load latency). Now tile t+1 and t+2 stay in
// flight across the barrier; only tile t (2 compute phases old) is waited on.
// Safety: barrier at iter t orders all reads of buf[(t-1)%3] (== (t+2)%3)
// before its overwrite; per-wave vmcnt(L)+barrier ensures tile t is in LDS.

__device__ __forceinline__ int frag_off(int rr, int lkb) {   // ushort offset
  return rr * 32 + ((lkb ^ ((rr >> 1) & 3)) * 8);
}

// ---------------- grouped GEMM A: h = silu(x@w1) * (x@w3) ----------------
// 8 waves (512 thr), 128x128 tile, wave tile 64x32 (R5-proven structure).
// L = 3 global_load_lds per wave per tile -> main-loop wait = vmcnt(3).
__global__ __launch_bounds__(512) void gemm_h_kernel(
    const ushort* __restrict__ xb, const ushort* __restrict__ w1t,
    const ushort* __restrict__ w3t, const int* __restrict__ pair_token,
    const int* __restrict__ counts, const int* __restrict__ offsets,
    ushort* __restrict__ hbuf) {
  int e = blockIdx.x;                 // expert == XCD (affinity heuristic)
  int mt = blockIdx.y;
  int cnt = counts[e];
  int m0 = mt * 128;
  if (m0 >= cnt) return;
  int base = offsets[e];
  int f0 = blockIdx.z * 128;

  __shared__ ushort As[3][4096], B1s[3][4096], B3s[3][4096];   // 72 KB total

  int tid = threadIdx.x;
  int w = tid >> 6, l = tid & 63;     // w in 0..7
  int q = l >> 2, s = l & 3;

  int row = w * 16 + q;
  int g = s ^ ((row >> 1) & 3);       // swizzled global k-chunk

  int pA = base + m0 + row; if (pA >= base + cnt) pA = base + cnt - 1;
  const ushort* gA  = xb + (size_t)pair_token[pA] * H + g * 8;
  const ushort* gB1 = w1t + ((size_t)e * F + f0 + row) * H + g * 8;
  const ushort* gB3 = w3t + ((size_t)e * F + f0 + row) * H + g * 8;
  int lofs = w * 512;                 // wave staging base, ushort offset

  int wm = w >> 2, wn = w & 3;        // wave tile: rows wm*64+, cols wn*32+
  int lr = l & 15, lkb = l >> 4;

  int offA[4], offB[2];
#pragma unroll
  for (int ms = 0; ms < 4; ++ms) offA[ms] = frag_off(wm * 64 + ms * 16 + lr, lkb);
#pragma unroll
  for (int ns = 0; ns < 2; ++ns) offB[ns] = frag_off(wn * 32 + ns * 16 + lr, lkb);

  f32x4 c1[4][2], c3[4][2];
#pragma unroll
  for (int a = 0; a < 4; ++a)
#pragma unroll
    for (int b = 0; b < 2; ++b) { c1[a][b] = (f32x4)0.f; c3[a][b] = (f32x4)0.f; }

  // prologue: stage k-tiles 0 and 1
  async_copy16(gA,  &As[0][lofs]);
  async_copy16(gB1, &B1s[0][lofs]);
  async_copy16(gB3, &B3s[0][lofs]);
  gA += BK; gB1 += BK; gB3 += BK;
  async_copy16(gA,  &As[1][lofs]);
  async_copy16(gB1, &B1s[1][lofs]);
  async_copy16(gB3, &B3s[1][lofs]);
  gA += BK; gB1 += BK; gB3 += BK;

  const int NT = H / BK;              // 32
  int b0 = 0, b1 = 1, b2 = 2;
  for (int t = 0; t < NT; ++t) {
    if (t < NT - 1) {
      asm volatile("s_waitcnt vmcnt(3)" ::: "memory");   // tile t landed; t+1 in flight
    } else {
      asm volatile("s_waitcnt vmcnt(0)" ::: "memory");   // last tile: full drain
    }
    __builtin_amdgcn_s_barrier();
    __builtin_amdgcn_sched_barrier(0);                   // pin ds_reads below barrier

    if (t + 2 < NT) {                 // stage tile t+2 into b2 (buffer of t-1)
      async_copy16(gA,  &As[b2][lofs]);
      async_copy16(gB1, &B1s[b2][lofs]);
      async_copy16(gB3, &B3s[b2][lofs]);
      gA += BK; gB1 += BK; gB3 += BK;
    }

    short8 af[4], b1f[2], b3f[2];
#pragma unroll
    for (int ms = 0; ms < 4; ++ms) af[ms] = *(const short8*)(&As[b0][0] + offA[ms]);
#pragma unroll
    for (int ns = 0; ns < 2; ++ns) {
      b1f[ns] = *(const short8*)(&B1s[b0][0] + offB[ns]);
      b3f[ns] = *(const short8*)(&B3s[b0][0] + offB[ns]);
    }
#pragma unroll
    for (int ms = 0; ms < 4; ++ms)
#pragma unroll
      for (int ns = 0; ns < 2; ++ns) {
        c1[ms][ns] = __builtin_amdgcn_mfma_f32_16x16x32_bf16(af[ms], b1f[ns], c1[ms][ns], 0, 0, 0);
        c3[ms][ns] = __builtin_amdgcn_mfma_f32_16x16x32_bf16(af[ms], b3f[ns], c3[ms][ns], 0, 0, 0);
      }

    int tmp = b0; b0 = b1; b1 = b2; b2 = tmp;   // rotate buffers
  }

#pragma unroll
  for (int ms = 0; ms < 4; ++ms)
#pragma unroll
    for (int ns = 0; ns < 2; ++ns)
#pragma unroll
      for (int rg = 0; rg < 4; ++rg) {
        int ml = wm * 64 + ms * 16 + (l >> 4) * 4 + rg;   // C/D: row=(lane>>4)*4+reg
        if (m0 + ml < cnt) {
          int nl = wn * 32 + ns * 16 + (l & 15);          // col=lane&15
          float gg = c1[ms][ns][rg], u = c3[ms][ns][rg];
          float hv = gg / (1.f + __expf(-gg)) * u;        // silu(g)*u
          hbuf[(size_t)(base + m0 + ml) * F + f0 + nl] = f2bf(hv);
        }
      }
}

// ---------------- grouped GEMM B: po = weight * (h @ w2), per-pair rows -------
// 4 waves, 128x128, wave 64x64 (R5-proven structure) + 3-buffer counted-vmcnt
// pipeline. L = 4 global_load_lds per wave per tile -> main-loop vmcnt(4).
__global__ __launch_bounds__(256) void gemm_out_kernel(
    const ushort* __restrict__ hbuf, const ushort* __restrict__ w2t,
    const float* __restrict__ pair_weight, const int* __restrict__ counts,
    const int* __restrict__ offsets, float* __restrict__ po) {
  int e = blockIdx.x;                 // expert == XCD
  int mt = blockIdx.y;
  int cnt = counts[e];
  int m0 = mt * 128;
  if (m0 >= cnt) return;
  int base = offsets[e];
  int n0 = blockIdx.z * 128;

  __shared__ ushort As[3][4096], Bs[3][4096];   // 48 KB
  __shared__ float wt_s[128];

  int tid = threadIdx.x;
  int w = tid >> 6, l = tid & 63;     // w in 0..3
  int q = l >> 2, s = l & 3;

  if (tid < 128) {
    int p = base + m0 + tid;
    if (p >= base + cnt) p = base + cnt - 1;
    wt_s[tid] = pair_weight[p];
  }

  // staging: wave w stages rows [w*32, w*32+32) of A and B (2 copies each)
  int r0 = w * 32 + q, r1 = r0 + 16;
  int g0 = s ^ ((r0 >> 1) & 3), g1 = s ^ ((r1 >> 1) & 3);
  int p0 = base + m0 + r0; if (p0 >= base + cnt) p0 = base + cnt - 1;
  int p1 = base + m0 + r1; if (p1 >= base + cnt) p1 = base + cnt - 1;
  const ushort* gAa = hbuf + (size_t)p0 * F + g0 * 8;
  const ushort* gAb = hbuf + (size_t)p1 * F + g1 * 8;
  const ushort* gBa = w2t + ((size_t)e * H + n0 + r0) * F + g0 * 8;
  const ushort* gBb = w2t + ((size_t)e * H + n0 + r1) * F + g1 * 8;
  int lofs = w * 1024;                // row (w*32) * 32 ushorts

  int wm = w >> 1, wn = w & 1;        // wave tile: rows wm*64+, cols wn*64+
  int lr = l & 15, lkb = l >> 4;

  int offA[4], offB[4];
#pragma unroll
  for (int ms = 0; ms < 4; ++ms) offA[ms] = frag_off(wm * 64 + ms * 16 + lr, lkb);
#pragma unroll
  for (int ns = 0; ns < 4; ++ns) offB[ns] = frag_off(wn * 64 + ns * 16 + lr, lkb);

  f32x4 cc[4][4];
#pragma unroll
  for (int a = 0; a < 4; ++a)
#pragma unroll
    for (int b = 0; b < 4; ++b) cc[a][b] = (f32x4)0.f;

  // prologue: stage k-tiles 0 and 1
  async_copy16(gAa, &As[0][lofs]);
  async_copy16(gAb, &As[0][lofs + 512]);
  async_copy16(gBa, &Bs[0][lofs]);
  async_copy16(gBb, &Bs[0][lofs + 512]);
  gAa += BK; gAb += BK; gBa += BK; gBb += BK;
  async_copy16(gAa, &As[1][lofs]);
  async_copy16(gAb, &As[1][lofs + 512]);
  async_copy16(gBa, &Bs[1][lofs]);
  async_copy16(gBb, &Bs[1][lofs + 512]);
  gAa += BK; gAb += BK; gBa += BK; gBb += BK;

  const int NT = F / BK;              // 64
  int b0 = 0, b1 = 1, b2 = 2;
  for (int t = 0; t < NT; ++t) {
    if (t < NT - 1) {
      asm volatile("s_waitcnt vmcnt(4)" ::: "memory");   // tile t landed; t+1 in flight
    } else {
      asm volatile("s_waitcnt vmcnt(0)" ::: "memory");
    }
    __builtin_amdgcn_s_barrier();
    __builtin_amdgcn_sched_barrier(0);

    if (t + 2 < NT) {
      async_copy16(gAa, &As[b2][lofs]);
      async_copy16(gAb, &As[b2][lofs + 512]);
      async_copy16(gBa, &Bs[b2][lofs]);
      async_copy16(gBb, &Bs[b2][lofs + 512]);
      gAa += BK; gAb += BK; gBa += BK; gBb += BK;
    }

    short8 af[4], bf_[4];
#pragma unroll
    for (int ms = 0; ms < 4; ++ms) af[ms] = *(const short8*)(&As[b0][0] + offA[ms]);
#pragma unroll
    for (int ns = 0; ns < 4; ++ns) bf_[ns] = *(const short8*)(&Bs[b0][0] + offB[ns]);
#pragma unroll
    for (int ms = 0; ms < 4; ++ms)
#pragma unroll
      for (int ns = 0; ns < 4; ++ns)
        cc[ms][ns] = __builtin_amdgcn_mfma_f32_16x16x32_bf16(af[ms], bf_[ns], cc[ms][ns], 0, 0, 0);

    int tmp = b0; b0 = b1; b1 = b2; b2 = tmp;
  }

#pragma unroll
  for (int ms = 0; ms < 4; ++ms)
#pragma unroll
    for (int ns = 0; ns < 4; ++ns)
#pragma unroll
      for (int rg = 0; rg < 4; ++rg) {
        int ml = wm * 64 + ms * 16 + (l >> 4) * 4 + rg;
        if (m0 + ml < cnt) {
          int nl = wn * 64 + ns * 16 + (l & 15);
          po[(size_t)(base + m0 + ml) * H + n0 + nl] = cc[ms][ns][rg] * wt_s[ml];
        }
      }
}

// ---------------- combine: y[t] = po[slot0] + po[slot1] ----------------
__global__ __launch_bounds__(256) void combine_kernel(
    const float* __restrict__ po, const int* __restrict__ pair_slot,
    float* __restrict__ y) {
  int idx = blockIdx.x * 256 + threadIdx.x;    // over T*H/4
  int t = idx >> 8;                            // H/4 = 256 float4 per token
  int c = (idx & 255) * 4;
  int s0 = pair_slot[t * 2], s1 = pair_slot[t * 2 + 1];
  float4 a = *(const float4*)(po + (size_t)s0 * H + c);
  float4 b = *(const float4*)(po + (size_t)s1 * H + c);
  float4 o = make_float4(a.x + b.x, a.y + b.y, a.z + b.z, a.w + b.w);
  *(float4*)(y + (size_t)t * H + c) = o;
}

extern "C" void kernel_launch(void* const* d_in, const int* in_sizes, int n_in,
                              void* d_out, int out_size, void* d_ws, size_t ws_size,
                              hipStream_t stream) {
  const float* x  = (const float*)d_in[0];
  const float* gw = (const float*)d_in[1];
  const float* w1 = (const float*)d_in[2];
  const float* w3 = (const float*)d_in[3];
  const float* w2 = (const float*)d_in[4];
  float* y = (float*)d_out;                       // [T, H] fp32
  float* logits_out = y + (size_t)T_TOK * H;      // [T, E] fp32 (output #2)

  char* ws = (char*)d_ws;
  size_t off = 0;
  auto alloc = [&](size_t bytes) {
    char* p = ws + off;
    off += (bytes + 255) & ~size_t(255);
    return p;
  };
  ushort* xb   = (ushort*)alloc((size_t)T_TOK * H * 2);
  ushort* w1t  = (ushort*)alloc((size_t)E * F * H * 2);
  ushort* w3t  = (ushort*)alloc((size_t)E * F * H * 2);
  ushort* w2t  = (ushort*)alloc((size_t)E * H * F * 2);
  ushort* hbuf = (ushort*)alloc((size_t)(NPAIR + 128) * F * 2);
  int*   pair_token  = (int*)alloc(NPAIR * 4);
  float* pair_weight = (float*)alloc(NPAIR * 4);
  int*   pair_slot   = (int*)alloc(NPAIR * 4);
  int*   sel   = (int*)alloc(T_TOK * 2 * 4);
  float* selw  = (float*)alloc(T_TOK * 2 * 4);
  int*   lrank = (int*)alloc(NPAIR * 4);
  int* counts  = (int*)alloc(E * 4);
  int* offsets = (int*)alloc(E * 4);
  int* blkcnt  = (int*)alloc(NB * E * 4);
  int* blkbase = (int*)alloc(NB * E * 4);
  // po aliases w1t: w1t (32 MB) is dead after gemm_h; po needs NPAIR*H*4 = 32 MB.
  float* po = (float*)w1t;

  router_kernel<<<T_TOK / 4, 256, 0, stream>>>(x, gw, logits_out, sel, selw, xb);
  hist_kernel<<<NB, 256, 0, stream>>>(sel, lrank, blkcnt);
  offsets_kernel<<<1, NB * E, 0, stream>>>(blkcnt, counts, offsets, blkbase);
  scatter_kernel<<<NB, 256, 0, stream>>>(sel, selw, lrank, blkbase,
                                         pair_token, pair_weight, pair_slot);
  transpose_cast13_kernel<<<dim3(F / 64, H / 64, 2 * E), 256, 0, stream>>>(w1, w3, w1t, w3t);
  transpose_cast_kernel<<<dim3(H / 64, F / 64, E), 256, 0, stream>>>(w2, w2t, F, H);
  gemm_h_kernel<<<dim3(E, TM2, F / 128), 512, 0, stream>>>(xb, w1t, w3t, pair_token,
                                                           counts, offsets, hbuf);
  gemm_out_kernel<<<dim3(E, TM2, H / 128), 256, 0, stream>>>(hbuf, w2t, pair_weight,
                                                             counts, offsets, po);
  combine_kernel<<<(T_TOK * H / 4) / 256, 256, 0, stream>>>(po, pair_slot, y);
}